// Round 5
// baseline (140.825 us; speedup 1.0000x reference)
//
#include <hip/hip_runtime.h>

#define NTOK 2048
#define DD   128
#define CHK  64
#define PCH  16     // chunks per sequence-part
#define EW   32     // e-slice width per block

typedef __attribute__((ext_vector_type(8))) short bf16x8;
typedef __attribute__((ext_vector_type(4))) float f32x4;
typedef unsigned short u16;

#define MFMA(a,b,c) __builtin_amdgcn_mfma_f32_16x16x32_bf16(a,b,c,0,0,0)

__device__ __forceinline__ u16 f2bf(float f){
  union { float f; unsigned u; } x; x.f = f;
  return (u16)((x.u + 0x7fffu + ((x.u >> 16) & 1u)) >> 16);
}
// XOR-swizzle 16B units within 128B windows by row&7
__device__ __forceinline__ int swz(int r, int c, int re){
  int b = (r*re + c)*2;
  return b ^ ((r & 7) << 4);
}
__device__ __forceinline__ void lds_w1(u16* a, int r, int c, int re, u16 v){
  *(u16*)((char*)a + swz(r,c,re)) = v;
}
__device__ __forceinline__ void lds_w4(u16* a, int r, int c, int re, ushort4 v){
  *(ushort4*)((char*)a + swz(r,c,re)) = v;
}
__device__ __forceinline__ bf16x8 lds_r8(const u16* a, int r, int c, int re){
  return *(const bf16x8*)((const char*)a + swz(r,c,re));
}

// ================= pass 1: per (head, e-slice, seq-part) chunk scan =================
__global__ __launch_bounds__(256) void gla_part(
    const float* __restrict__ Qg, const float* __restrict__ Kg,
    const float* __restrict__ Vg, const float* __restrict__ Gg,
    float* __restrict__ Og, float* __restrict__ Smid, float* __restrict__ Bpre)
{
  __shared__ u16 sKh [CHK*DD];   // K_hat [s][d]          16 KB
  __shared__ u16 sKhT[DD*CHK];   // K_hat^T [d][s]        16 KB
  __shared__ u16 sVT [EW*CHK];   // V^T slice [e][s]       4 KB
  __shared__ u16 sST [EW*DD];    // S^T [e][d] snapshot    8 KB
  __shared__ u16 sPb [CHK*CHK];  // masked P [t][s]        8 KB

  const int tid = threadIdx.x;
  const int w = tid >> 6, l = tid & 63, lr = l & 15, lh = l >> 4;
  // gid bits: [0:2]=head-low (XCD), [3:4]=e-slice, [5]=part, [6:8]=head-high
  const int gid  = blockIdx.x;
  const int head = (gid & 7) | (((gid >> 6) & 7) << 3);
  const int e0   = ((gid >> 3) & 3) * EW;
  const int part = (gid >> 5) & 1;
  const int tbase = part * (PCH*CHK);

  const float* Qh = Qg + (size_t)head*NTOK*DD;
  const float* Kh = Kg + (size_t)head*NTOK*DD;
  const float* Vh = Vg + (size_t)head*NTOK*DD;
  const float* Gh = Gg + (size_t)head*NTOK;
  float* Oh = Og + (size_t)head*NTOK*DD;

  f32x4 S00 = {}, S01 = {}, S10 = {}, S11 = {};  // S[d][e] slice in MFMA C-layout
  float4 kpre[8], vpre[2], qpre[8];
  float gst;

  auto loads = [&](int c){
    const int t0 = tbase + c*CHK;
    gst = Gh[t0 + l];                              // G first (waited first)
    const int srow = t0 + (tid >> 2);
    const float* kp = Kh + (size_t)srow*DD + 4*(tid & 3);
    #pragma unroll
    for (int i=0;i<8;++i) kpre[i] = *(const float4*)(kp + 16*i);
    const float* vp = Vh + (size_t)srow*DD + e0 + 4*(tid & 3);
    #pragma unroll
    for (int i=0;i<2;++i) vpre[i] = *(const float4*)(vp + 16*i);
    const float* qp = Qh + (size_t)(t0 + w*16 + lr)*DD + lh*8;
    #pragma unroll
    for (int i=0;i<4;++i){
      qpre[2*i]   = *(const float4*)(qp + 32*i);
      qpre[2*i+1] = *(const float4*)(qp + 32*i + 4);
    }
  };

  float ckl_s, cq, scc, bl63;
  auto scan = [&](){
    float li = 1.f/(1.f + expf(-gst));
    float x  = log2f(li);
    #pragma unroll
    for (int off=1; off<64; off<<=1){
      float y = __shfl_up(x, off, 64);
      if (l >= off) x += y;
    }
    bl63 = __shfl(x, 63, 64);
    scc  = exp2f(bl63);
    cq   = exp2f(__shfl(x, w*16 + lr, 64));
    float cklr = exp2f(-x) * (1.f - li);            // row l's k-hat scale
    ckl_s = __shfl(cklr, w*16 + (l >> 2), 64);      // for row tid>>2
  };

  loads(0);
  scan();
  float bsum = 0.f;
  if (part == 1 && e0 == 0 && tid == 0) Bpre[head*PCH] = 0.f;

  for (int c=0; c<PCH; ++c){
    __syncthreads();                 // prev chunk's LDS reads done

    // ---- conversion phase (regs -> bf16 LDS) ----
    const int srow = tid >> 2;
    #pragma unroll
    for (int i=0;i<8;++i){
      float4 kf = kpre[i];
      int d = 4*((tid & 3) + 4*i);
      u16 b0=f2bf(kf.x*ckl_s), b1=f2bf(kf.y*ckl_s), b2=f2bf(kf.z*ckl_s), b3=f2bf(kf.w*ckl_s);
      lds_w4(sKh, srow, d, DD, make_ushort4(b0,b1,b2,b3));
      lds_w1(sKhT, d+0, srow, CHK, b0);
      lds_w1(sKhT, d+1, srow, CHK, b1);
      lds_w1(sKhT, d+2, srow, CHK, b2);
      lds_w1(sKhT, d+3, srow, CHK, b3);
    }
    #pragma unroll
    for (int i=0;i<2;++i){
      float4 vf = vpre[i];
      int e = 4*((tid & 3) + 4*i);
      lds_w1(sVT, e+0, srow, CHK, f2bf(vf.x));
      lds_w1(sVT, e+1, srow, CHK, f2bf(vf.y));
      lds_w1(sVT, e+2, srow, CHK, f2bf(vf.z));
      lds_w1(sVT, e+3, srow, CHK, f2bf(vf.w));
    }
    {
      const int dbase = w*32 + lh*4;
      #pragma unroll
      for (int r=0;r<4;++r){
        lds_w1(sST, lr,    dbase + r,      DD, f2bf(S00[r]));
        lds_w1(sST, 16+lr, dbase + r,      DD, f2bf(S01[r]));
        lds_w1(sST, lr,    dbase + 16 + r, DD, f2bf(S10[r]));
        lds_w1(sST, 16+lr, dbase + 16 + r, DD, f2bf(S11[r]));
      }
    }
    bf16x8 qA[4];
    #pragma unroll
    for (int ks=0;ks<4;++ks){
      float4 a = qpre[2*ks], b = qpre[2*ks+1];
      bf16x8 t;
      t[0]=(short)f2bf(a.x*cq); t[1]=(short)f2bf(a.y*cq);
      t[2]=(short)f2bf(a.z*cq); t[3]=(short)f2bf(a.w*cq);
      t[4]=(short)f2bf(b.x*cq); t[5]=(short)f2bf(b.y*cq);
      t[6]=(short)f2bf(b.z*cq); t[7]=(short)f2bf(b.w*cq);
      qA[ks] = t;
    }
    if (c+1 < PCH) loads(c+1);       // issue next chunk a full chunk ahead (WAR-safe)
    __syncthreads();                 // bf16 LDS visible

    // ---- phase 1: O1 = Qt*S_in ; P = Qt*Kh^T ----
    f32x4 oacc0 = {}, oacc1 = {};
    f32x4 p0 = {}, p1 = {}, p2 = {}, p3 = {};
    #pragma unroll
    for (int ks=0;ks<4;++ks){
      const int kk = ks*32 + lh*8;
      bf16x8 a = qA[ks];
      oacc0 = MFMA(a, lds_r8(sST, lr,    kk, DD), oacc0);
      oacc1 = MFMA(a, lds_r8(sST, 16+lr, kk, DD), oacc1);
      p0 = MFMA(a, lds_r8(sKh, lr,    kk, DD), p0);
      p1 = MFMA(a, lds_r8(sKh, 16+lr, kk, DD), p1);
      p2 = MFMA(a, lds_r8(sKh, 32+lr, kk, DD), p2);
      p3 = MFMA(a, lds_r8(sKh, 48+lr, kk, DD), p3);
    }
    // ---- causal mask -> Pb (own rows only) ----
    {
      const int t = w*16 + lh*4;
      #pragma unroll
      for (int r=0;r<4;++r){
        int tt = t + r;
        lds_w1(sPb, tt, lr,    CHK, f2bf((lr    <= tt) ? p0[r] : 0.f));
        lds_w1(sPb, tt, 16+lr, CHK, f2bf((16+lr <= tt) ? p1[r] : 0.f));
        lds_w1(sPb, tt, 32+lr, CHK, f2bf((32+lr <= tt) ? p2[r] : 0.f));
        lds_w1(sPb, tt, 48+lr, CHK, f2bf((48+lr <= tt) ? p3[r] : 0.f));
      }
    }
    asm volatile("s_waitcnt lgkmcnt(0)" ::: "memory");
    __builtin_amdgcn_sched_barrier(0);

    // ---- phase 2: O2 += P*V ; S += Khat^T*V ----
    #pragma unroll
    for (int k2=0;k2<2;++k2){
      const int kk = k2*32 + lh*8;
      bf16x8 vb0 = lds_r8(sVT, lr,    kk, CHK);
      bf16x8 vb1 = lds_r8(sVT, 16+lr, kk, CHK);
      bf16x8 pa  = lds_r8(sPb, w*16 + lr, kk, CHK);
      oacc0 = MFMA(pa, vb0, oacc0);
      oacc1 = MFMA(pa, vb1, oacc1);
      bf16x8 ka0 = lds_r8(sKhT, w*32 + lr,      kk, CHK);
      bf16x8 ka1 = lds_r8(sKhT, w*32 + 16 + lr, kk, CHK);
      S00 = MFMA(ka0, vb0, S00);
      S01 = MFMA(ka0, vb1, S01);
      S10 = MFMA(ka1, vb0, S10);
      S11 = MFMA(ka1, vb1, S11);
    }
    #pragma unroll
    for (int r=0;r<4;++r){ S00[r]*=scc; S01[r]*=scc; S10[r]*=scc; S11[r]*=scc; }

    // ---- write O chunk (fp32) ----
    {
      float* op = Oh + (size_t)(tbase + c*CHK + w*16 + lh*4)*DD + e0;
      #pragma unroll
      for (int r=0;r<4;++r){
        op[r*DD + lr]      = oacc0[r];
        op[r*DD + 16 + lr] = oacc1[r];
      }
    }
    // ---- tail: scan for next chunk (off the critical path) ----
    if (c+1 < PCH){
      if (part == 1){
        bsum += bl63;
        if (e0 == 0 && tid == 0) Bpre[head*PCH + c + 1] = bsum;
      }
      scan();
    }
  }

  if (part == 0){      // hand off S_mid (state after token PCH*CHK-1)
    float* sm = Smid + (size_t)head*DD*DD + e0;
    const int dbase = w*32 + lh*4;
    #pragma unroll
    for (int r=0;r<4;++r){
      sm[(size_t)(dbase + r)*DD + lr]           = S00[r];
      sm[(size_t)(dbase + r)*DD + 16 + lr]      = S01[r];
      sm[(size_t)(dbase + 16 + r)*DD + lr]      = S10[r];
      sm[(size_t)(dbase + 16 + r)*DD + 16 + lr] = S11[r];
    }
  }
}

// ================= pass 2: O[second half] += 2^{b} Q · S_mid =================
__global__ __launch_bounds__(256) void gla_fix(
    const float* __restrict__ Qg, const float* __restrict__ Gg,
    float* __restrict__ Og, const float* __restrict__ Smid,
    const float* __restrict__ Bpre)
{
  __shared__ u16 sS[DD*DD];       // S_mid^T [e][d] bf16, 32 KB
  const int tid = threadIdx.x;
  const int w = tid >> 6, l = tid & 63, lr = l & 15, lh = l >> 4;
  const int head = blockIdx.x >> 4, c = blockIdx.x & 15;
  const int t0 = PCH*CHK + c*CHK;

  { // stage S^T
    const int d = tid >> 1, eb = (tid & 1)*64;
    const float* sp = Smid + (size_t)head*DD*DD + (size_t)d*DD + eb;
    #pragma unroll
    for (int j=0;j<16;++j){
      float4 f = *(const float4*)(sp + 4*j);
      lds_w1(sS, eb + 4*j + 0, d, DD, f2bf(f.x));
      lds_w1(sS, eb + 4*j + 1, d, DD, f2bf(f.y));
      lds_w1(sS, eb + 4*j + 2, d, DD, f2bf(f.z));
      lds_w1(sS, eb + 4*j + 3, d, DD, f2bf(f.w));
    }
  }
  // gate scan (within chunk) + part-prefix
  float gst = Gg[(size_t)head*NTOK + t0 + l];
  float li = 1.f/(1.f + expf(-gst));
  float x  = log2f(li);
  #pragma unroll
  for (int off=1; off<64; off<<=1){
    float y = __shfl_up(x, off, 64);
    if (l >= off) x += y;
  }
  const float cq = exp2f(__shfl(x, w*16 + lr, 64) + Bpre[head*PCH + c]);

  bf16x8 qA[4];
  const float* qp = Qg + (size_t)head*NTOK*DD + (size_t)(t0 + w*16 + lr)*DD + lh*8;
  #pragma unroll
  for (int ks=0;ks<4;++ks){
    float4 a = *(const float4*)(qp + ks*32);
    float4 b = *(const float4*)(qp + ks*32 + 4);
    bf16x8 t;
    t[0]=(short)f2bf(a.x*cq); t[1]=(short)f2bf(a.y*cq);
    t[2]=(short)f2bf(a.z*cq); t[3]=(short)f2bf(a.w*cq);
    t[4]=(short)f2bf(b.x*cq); t[5]=(short)f2bf(b.y*cq);
    t[6]=(short)f2bf(b.z*cq); t[7]=(short)f2bf(b.w*cq);
    qA[ks] = t;
  }
  __syncthreads();

  f32x4 o0={},o1={},o2={},o3={},o4={},o5={},o6={},o7={};
  #pragma unroll
  for (int ks=0;ks<4;++ks){
    const int kk = ks*32 + lh*8;
    bf16x8 a = qA[ks];
    o0 = MFMA(a, lds_r8(sS, lr,      kk, DD), o0);
    o1 = MFMA(a, lds_r8(sS, 16+lr,   kk, DD), o1);
    o2 = MFMA(a, lds_r8(sS, 32+lr,   kk, DD), o2);
    o3 = MFMA(a, lds_r8(sS, 48+lr,   kk, DD), o3);
    o4 = MFMA(a, lds_r8(sS, 64+lr,   kk, DD), o4);
    o5 = MFMA(a, lds_r8(sS, 80+lr,   kk, DD), o5);
    o6 = MFMA(a, lds_r8(sS, 96+lr,   kk, DD), o6);
    o7 = MFMA(a, lds_r8(sS, 112+lr,  kk, DD), o7);
  }
  float* op = Og + (size_t)head*NTOK*DD + (size_t)(t0 + w*16 + lh*4)*DD;
  #pragma unroll
  for (int r=0;r<4;++r){
    op[r*DD + lr]       += o0[r];
    op[r*DD + 16 + lr]  += o1[r];
    op[r*DD + 32 + lr]  += o2[r];
    op[r*DD + 48 + lr]  += o3[r];
    op[r*DD + 64 + lr]  += o4[r];
    op[r*DD + 80 + lr]  += o5[r];
    op[r*DD + 96 + lr]  += o6[r];
    op[r*DD + 112 + lr] += o7[r];
  }
}

extern "C" void kernel_launch(void* const* d_in, const int* in_sizes, int n_in,
                              void* d_out, int out_size, void* d_ws, size_t ws_size,
                              hipStream_t stream)
{
  const float* q = (const float*)d_in[0];
  const float* k = (const float*)d_in[1];
  const float* v = (const float*)d_in[2];
  const float* g = (const float*)d_in[3];
  float* out = (float*)d_out;
  float* Smid = (float*)d_ws;                                  // 64*128*128*4 = 4 MB
  float* Bpre = (float*)((char*)d_ws + (size_t)64*DD*DD*4);    // 64*16*4 = 4 KB

  gla_part<<<dim3(512),  dim3(256), 0, stream>>>(q, k, v, g, out, Smid, Bpre);
  gla_fix <<<dim3(1024), dim3(256), 0, stream>>>(q, g, out, Smid, Bpre);
}

// Round 6
// 140.585 us; speedup vs baseline: 1.0017x; 1.0017x over previous
//
#include <hip/hip_runtime.h>

#define NTOK 2048
#define DD   128
#define CHK  64
#define PCH  16     // chunks per sequence-part
#define EW   32     // e-slice width per block

typedef __attribute__((ext_vector_type(8))) short bf16x8;
typedef __attribute__((ext_vector_type(4))) float f32x4;
typedef unsigned short u16;

#define MFMA(a,b,c) __builtin_amdgcn_mfma_f32_16x16x32_bf16(a,b,c,0,0,0)

// barrier WITHOUT vmcnt drain: LDS-visibility only; global loads stay in flight
#define SBAR() do{ __builtin_amdgcn_sched_barrier(0); \
  asm volatile("s_waitcnt lgkmcnt(0)" ::: "memory"); \
  __builtin_amdgcn_s_barrier(); \
  __builtin_amdgcn_sched_barrier(0); }while(0)
#define VWAIT() do{ asm volatile("s_waitcnt vmcnt(0)" ::: "memory"); \
  __builtin_amdgcn_sched_barrier(0); }while(0)

__device__ __forceinline__ u16 f2bf(float f){
  union { float f; unsigned u; } x; x.f = f;
  return (u16)((x.u + 0x7fffu + ((x.u >> 16) & 1u)) >> 16);
}
// XOR-swizzle 16B units within 128B windows by row&7
__device__ __forceinline__ int swz(int r, int c, int re){
  int b = (r*re + c)*2;
  return b ^ ((r & 7) << 4);
}
__device__ __forceinline__ void lds_w1(u16* a, int r, int c, int re, u16 v){
  *(u16*)((char*)a + swz(r,c,re)) = v;
}
__device__ __forceinline__ void lds_w4(u16* a, int r, int c, int re, ushort4 v){
  *(ushort4*)((char*)a + swz(r,c,re)) = v;
}
__device__ __forceinline__ bf16x8 lds_r8(const u16* a, int r, int c, int re){
  return *(const bf16x8*)((const char*)a + swz(r,c,re));
}

// ================= pass 1: per (head, e-slice, seq-part) chunk scan =================
__global__ __launch_bounds__(256) void gla_part(
    const float* __restrict__ Qg, const float* __restrict__ Kg,
    const float* __restrict__ Vg, const float* __restrict__ Gg,
    float* __restrict__ Og, float* __restrict__ Smid, float* __restrict__ Bpre)
{
  __shared__ u16 sKh [CHK*DD];   // K_hat [s][d]          16 KB
  __shared__ u16 sKhT[DD*CHK];   // K_hat^T [d][s]        16 KB
  __shared__ u16 sVT [EW*CHK];   // V^T slice [e][s]       4 KB
  __shared__ u16 sST [EW*DD];    // S^T [e][d] snapshot    8 KB
  __shared__ u16 sPb [CHK*CHK];  // masked P [t][s]        8 KB

  const int tid = threadIdx.x;
  const int w = tid >> 6, l = tid & 63, lr = l & 15, lh = l >> 4;
  // gid bits: [0:2]=head-low (XCD), [3:4]=e-slice, [5]=part, [6:8]=head-high
  const int gid  = blockIdx.x;
  const int head = (gid & 7) | (((gid >> 6) & 7) << 3);
  const int e0   = ((gid >> 3) & 3) * EW;
  const int part = (gid >> 5) & 1;
  const int tbase = part * (PCH*CHK);

  const float* Qh = Qg + (size_t)head*NTOK*DD;
  const float* Kh = Kg + (size_t)head*NTOK*DD;
  const float* Vh = Vg + (size_t)head*NTOK*DD;
  const float* Gh = Gg + (size_t)head*NTOK;
  float* Oh = Og + (size_t)head*NTOK*DD;

  f32x4 S00 = {}, S01 = {}, S10 = {}, S11 = {};  // S[d][e] slice in MFMA C-layout
  float4 kt[2][4];    // K tiles: rows 4q..4q+3 x d-quads (j0, j0+16)
  float4 vpre[2], qpre[8];
  float gst;

  const int q4 = (tid >> 4) * 4;     // K-tile s-row base
  const int j0 = tid & 15;           // K-tile d-quad index

  auto loads = [&](int c){
    const int t0 = tbase + c*CHK;
    gst = Gh[t0 + l];                              // G first (waited first at scan)
    #pragma unroll
    for (int t=0;t<2;++t){
      const float* kp = Kh + (size_t)(t0 + q4)*DD + (j0 + 16*t)*4;
      #pragma unroll
      for (int r=0;r<4;++r) kt[t][r] = *(const float4*)(kp + r*DD);
    }
    const float* vp = Vh + (size_t)(t0 + (tid>>2))*DD + e0 + 4*(tid&3);
    #pragma unroll
    for (int i=0;i<2;++i) vpre[i] = *(const float4*)(vp + 16*i);
    const float* qp = Qh + (size_t)(t0 + w*16 + lr)*DD + lh*8;
    #pragma unroll
    for (int i=0;i<4;++i){
      qpre[2*i]   = *(const float4*)(qp + 32*i);
      qpre[2*i+1] = *(const float4*)(qp + 32*i + 4);
    }
  };

  float cklr, cq, scc, bl63;
  auto scan = [&](){
    float li = 1.f/(1.f + expf(-gst));
    float x  = log2f(li);
    #pragma unroll
    for (int off=1; off<64; off<<=1){
      float y = __shfl_up(x, off, 64);
      if (l >= off) x += y;
    }
    bl63 = __shfl(x, 63, 64);
    scc  = exp2f(bl63);
    cq   = exp2f(__shfl(x, w*16 + lr, 64));
    cklr = exp2f(-x) * (1.f - li);                 // lane l holds k-hat scale of row l
  };

  loads(0);
  scan();
  float bsum = 0.f;
  if (part == 1 && e0 == 0 && tid == 0) Bpre[head*PCH] = 0.f;

  for (int c=0; c<PCH; ++c){
    SBAR();            // A: all waves done reading prev chunk's LDS
    VWAIT();           // my reg-staged loads for chunk c have landed

    // ---- conversion phase (regs -> bf16 LDS, all wide writes) ----
    {
      const float cs0 = __shfl(cklr, q4+0, 64);
      const float cs1 = __shfl(cklr, q4+1, 64);
      const float cs2 = __shfl(cklr, q4+2, 64);
      const float cs3 = __shfl(cklr, q4+3, 64);
      #pragma unroll
      for (int t=0;t<2;++t){
        const int d0 = (j0 + 16*t)*4;
        ushort4 r0 = make_ushort4(f2bf(kt[t][0].x*cs0), f2bf(kt[t][0].y*cs0), f2bf(kt[t][0].z*cs0), f2bf(kt[t][0].w*cs0));
        ushort4 r1 = make_ushort4(f2bf(kt[t][1].x*cs1), f2bf(kt[t][1].y*cs1), f2bf(kt[t][1].z*cs1), f2bf(kt[t][1].w*cs1));
        ushort4 r2 = make_ushort4(f2bf(kt[t][2].x*cs2), f2bf(kt[t][2].y*cs2), f2bf(kt[t][2].z*cs2), f2bf(kt[t][2].w*cs2));
        ushort4 r3 = make_ushort4(f2bf(kt[t][3].x*cs3), f2bf(kt[t][3].y*cs3), f2bf(kt[t][3].z*cs3), f2bf(kt[t][3].w*cs3));
        lds_w4(sKh, q4+0, d0, DD, r0);
        lds_w4(sKh, q4+1, d0, DD, r1);
        lds_w4(sKh, q4+2, d0, DD, r2);
        lds_w4(sKh, q4+3, d0, DD, r3);
        lds_w4(sKhT, d0+0, q4, CHK, make_ushort4(r0.x, r1.x, r2.x, r3.x));
        lds_w4(sKhT, d0+1, q4, CHK, make_ushort4(r0.y, r1.y, r2.y, r3.y));
        lds_w4(sKhT, d0+2, q4, CHK, make_ushort4(r0.z, r1.z, r2.z, r3.z));
        lds_w4(sKhT, d0+3, q4, CHK, make_ushort4(r0.w, r1.w, r2.w, r3.w));
      }
    }
    {
      const int srow = tid >> 2;
      #pragma unroll
      for (int i=0;i<2;++i){
        float4 vf = vpre[i];
        int e = 4*((tid & 3) + 4*i);
        lds_w1(sVT, e+0, srow, CHK, f2bf(vf.x));
        lds_w1(sVT, e+1, srow, CHK, f2bf(vf.y));
        lds_w1(sVT, e+2, srow, CHK, f2bf(vf.z));
        lds_w1(sVT, e+3, srow, CHK, f2bf(vf.w));
      }
    }
    {
      const int dbase = w*32 + lh*4;
      lds_w4(sST, lr,    dbase,      DD, make_ushort4(f2bf(S00[0]), f2bf(S00[1]), f2bf(S00[2]), f2bf(S00[3])));
      lds_w4(sST, 16+lr, dbase,      DD, make_ushort4(f2bf(S01[0]), f2bf(S01[1]), f2bf(S01[2]), f2bf(S01[3])));
      lds_w4(sST, lr,    dbase + 16, DD, make_ushort4(f2bf(S10[0]), f2bf(S10[1]), f2bf(S10[2]), f2bf(S10[3])));
      lds_w4(sST, 16+lr, dbase + 16, DD, make_ushort4(f2bf(S11[0]), f2bf(S11[1]), f2bf(S11[2]), f2bf(S11[3])));
    }
    bf16x8 qA[4];
    #pragma unroll
    for (int ks=0;ks<4;++ks){
      float4 a = qpre[2*ks], b = qpre[2*ks+1];
      bf16x8 t;
      t[0]=(short)f2bf(a.x*cq); t[1]=(short)f2bf(a.y*cq);
      t[2]=(short)f2bf(a.z*cq); t[3]=(short)f2bf(a.w*cq);
      t[4]=(short)f2bf(b.x*cq); t[5]=(short)f2bf(b.y*cq);
      t[6]=(short)f2bf(b.z*cq); t[7]=(short)f2bf(b.w*cq);
      qA[ks] = t;
    }
    if (c+1 < PCH) loads(c+1);       // issue next chunk's loads; stay in flight across SBAR
    SBAR();                          // B: bf16 LDS visible (no vmcnt drain!)

    // ---- phase 1: O1 = Qt*S_in ; P = Qt*Kh^T ----
    f32x4 oacc0 = {}, oacc1 = {};
    f32x4 p0 = {}, p1 = {}, p2 = {}, p3 = {};
    #pragma unroll
    for (int ks=0;ks<4;++ks){
      const int kk = ks*32 + lh*8;
      bf16x8 a = qA[ks];
      oacc0 = MFMA(a, lds_r8(sST, lr,    kk, DD), oacc0);
      oacc1 = MFMA(a, lds_r8(sST, 16+lr, kk, DD), oacc1);
      p0 = MFMA(a, lds_r8(sKh, lr,    kk, DD), p0);
      p1 = MFMA(a, lds_r8(sKh, 16+lr, kk, DD), p1);
      p2 = MFMA(a, lds_r8(sKh, 32+lr, kk, DD), p2);
      p3 = MFMA(a, lds_r8(sKh, 48+lr, kk, DD), p3);
    }
    // ---- causal mask -> Pb (own rows only) ----
    {
      const int t = w*16 + lh*4;
      #pragma unroll
      for (int r=0;r<4;++r){
        int tt = t + r;
        lds_w1(sPb, tt, lr,    CHK, f2bf((lr    <= tt) ? p0[r] : 0.f));
        lds_w1(sPb, tt, 16+lr, CHK, f2bf((16+lr <= tt) ? p1[r] : 0.f));
        lds_w1(sPb, tt, 32+lr, CHK, f2bf((32+lr <= tt) ? p2[r] : 0.f));
        lds_w1(sPb, tt, 48+lr, CHK, f2bf((48+lr <= tt) ? p3[r] : 0.f));
      }
    }
    asm volatile("s_waitcnt lgkmcnt(0)" ::: "memory");
    __builtin_amdgcn_sched_barrier(0);

    // ---- phase 2: O2 += P*V ; S += Khat^T*V ----
    #pragma unroll
    for (int k2=0;k2<2;++k2){
      const int kk = k2*32 + lh*8;
      bf16x8 vb0 = lds_r8(sVT, lr,    kk, CHK);
      bf16x8 vb1 = lds_r8(sVT, 16+lr, kk, CHK);
      bf16x8 pa  = lds_r8(sPb, w*16 + lr, kk, CHK);
      oacc0 = MFMA(pa, vb0, oacc0);
      oacc1 = MFMA(pa, vb1, oacc1);
      bf16x8 ka0 = lds_r8(sKhT, w*32 + lr,      kk, CHK);
      bf16x8 ka1 = lds_r8(sKhT, w*32 + 16 + lr, kk, CHK);
      S00 = MFMA(ka0, vb0, S00);
      S01 = MFMA(ka0, vb1, S01);
      S10 = MFMA(ka1, vb0, S10);
      S11 = MFMA(ka1, vb1, S11);
    }
    #pragma unroll
    for (int r=0;r<4;++r){ S00[r]*=scc; S01[r]*=scc; S10[r]*=scc; S11[r]*=scc; }

    // ---- write O chunk (fp32) ----
    {
      float* op = Oh + (size_t)(tbase + c*CHK + w*16 + lh*4)*DD + e0;
      #pragma unroll
      for (int r=0;r<4;++r){
        op[r*DD + lr]      = oacc0[r];
        op[r*DD + 16 + lr] = oacc1[r];
      }
    }
    // ---- tail: scan for next chunk (off the critical path) ----
    if (c+1 < PCH){
      if (part == 1){
        bsum += bl63;
        if (e0 == 0 && tid == 0) Bpre[head*PCH + c + 1] = bsum;
      }
      scan();
    }
  }

  if (part == 0){      // hand off S_mid (state after token PCH*CHK-1)
    float* sm = Smid + (size_t)head*DD*DD + e0;
    const int dbase = w*32 + lh*4;
    #pragma unroll
    for (int r=0;r<4;++r){
      sm[(size_t)(dbase + r)*DD + lr]           = S00[r];
      sm[(size_t)(dbase + r)*DD + 16 + lr]      = S01[r];
      sm[(size_t)(dbase + 16 + r)*DD + lr]      = S10[r];
      sm[(size_t)(dbase + 16 + r)*DD + 16 + lr] = S11[r];
    }
  }
}

// ================= pass 2: O[second half] += 2^{b} Q · S_mid =================
__global__ __launch_bounds__(256) void gla_fix(
    const float* __restrict__ Qg, const float* __restrict__ Gg,
    float* __restrict__ Og, const float* __restrict__ Smid,
    const float* __restrict__ Bpre)
{
  __shared__ u16 sS[DD*DD];       // S_mid^T [e][d] bf16, 32 KB
  const int tid = threadIdx.x;
  const int w = tid >> 6, l = tid & 63, lr = l & 15, lh = l >> 4;
  const int head = blockIdx.x >> 4, c = blockIdx.x & 15;
  const int t0 = PCH*CHK + c*CHK;

  { // stage S^T
    const int d = tid >> 1, eb = (tid & 1)*64;
    const float* sp = Smid + (size_t)head*DD*DD + (size_t)d*DD + eb;
    #pragma unroll
    for (int j=0;j<16;++j){
      float4 f = *(const float4*)(sp + 4*j);
      lds_w1(sS, eb + 4*j + 0, d, DD, f2bf(f.x));
      lds_w1(sS, eb + 4*j + 1, d, DD, f2bf(f.y));
      lds_w1(sS, eb + 4*j + 2, d, DD, f2bf(f.z));
      lds_w1(sS, eb + 4*j + 3, d, DD, f2bf(f.w));
    }
  }
  // gate scan (within chunk) + part-prefix
  float gst = Gg[(size_t)head*NTOK + t0 + l];
  float li = 1.f/(1.f + expf(-gst));
  float x  = log2f(li);
  #pragma unroll
  for (int off=1; off<64; off<<=1){
    float y = __shfl_up(x, off, 64);
    if (l >= off) x += y;
  }
  const float cq = exp2f(__shfl(x, w*16 + lr, 64) + Bpre[head*PCH + c]);

  bf16x8 qA[4];
  const float* qp = Qg + (size_t)head*NTOK*DD + (size_t)(t0 + w*16 + lr)*DD + lh*8;
  #pragma unroll
  for (int ks=0;ks<4;++ks){
    float4 a = *(const float4*)(qp + ks*32);
    float4 b = *(const float4*)(qp + ks*32 + 4);
    bf16x8 t;
    t[0]=(short)f2bf(a.x*cq); t[1]=(short)f2bf(a.y*cq);
    t[2]=(short)f2bf(a.z*cq); t[3]=(short)f2bf(a.w*cq);
    t[4]=(short)f2bf(b.x*cq); t[5]=(short)f2bf(b.y*cq);
    t[6]=(short)f2bf(b.z*cq); t[7]=(short)f2bf(b.w*cq);
    qA[ks] = t;
  }
  __syncthreads();

  f32x4 o0={},o1={},o2={},o3={},o4={},o5={},o6={},o7={};
  #pragma unroll
  for (int ks=0;ks<4;++ks){
    const int kk = ks*32 + lh*8;
    bf16x8 a = qA[ks];
    o0 = MFMA(a, lds_r8(sS, lr,      kk, DD), o0);
    o1 = MFMA(a, lds_r8(sS, 16+lr,   kk, DD), o1);
    o2 = MFMA(a, lds_r8(sS, 32+lr,   kk, DD), o2);
    o3 = MFMA(a, lds_r8(sS, 48+lr,   kk, DD), o3);
    o4 = MFMA(a, lds_r8(sS, 64+lr,   kk, DD), o4);
    o5 = MFMA(a, lds_r8(sS, 80+lr,   kk, DD), o5);
    o6 = MFMA(a, lds_r8(sS, 96+lr,   kk, DD), o6);
    o7 = MFMA(a, lds_r8(sS, 112+lr,  kk, DD), o7);
  }
  float* op = Og + (size_t)head*NTOK*DD + (size_t)(t0 + w*16 + lh*4)*DD;
  #pragma unroll
  for (int r=0;r<4;++r){
    op[r*DD + lr]       += o0[r];
    op[r*DD + 16 + lr]  += o1[r];
    op[r*DD + 32 + lr]  += o2[r];
    op[r*DD + 48 + lr]  += o3[r];
    op[r*DD + 64 + lr]  += o4[r];
    op[r*DD + 80 + lr]  += o5[r];
    op[r*DD + 96 + lr]  += o6[r];
    op[r*DD + 112 + lr] += o7[r];
  }
}

extern "C" void kernel_launch(void* const* d_in, const int* in_sizes, int n_in,
                              void* d_out, int out_size, void* d_ws, size_t ws_size,
                              hipStream_t stream)
{
  const float* q = (const float*)d_in[0];
  const float* k = (const float*)d_in[1];
  const float* v = (const float*)d_in[2];
  const float* g = (const float*)d_in[3];
  float* out = (float*)d_out;
  float* Smid = (float*)d_ws;                                  // 64*128*128*4 = 4 MB
  float* Bpre = (float*)((char*)d_ws + (size_t)64*DD*DD*4);    // 64*16*4 = 4 KB

  gla_part<<<dim3(512),  dim3(256), 0, stream>>>(q, k, v, g, out, Smid, Bpre);
  gla_fix <<<dim3(1024), dim3(256), 0, stream>>>(q, g, out, Smid, Bpre);
}